// Round 4
// baseline (1168.817 us; speedup 1.0000x reference)
//
#include <hip/hip_runtime.h>
#include <hip/hip_bf16.h>

// GraphSAGE on MFMA, R3:
//  - per layer: g = h @ Bck^T (split-bf16, 3-product, fp32-grade)
//  - aggregate: h_next[n] = relu(g_self[n] + mean_j g_neigh[nb[j]]),
//    written as bf16 hi/lo planes (layers 1-3) so the next GEMM stages A
//    with pure b128 copies; layer-4 aggregate writes fp32 in-place over g_self.
//  - aggregate is XCD-column-sharded: block b -> col slice (b&7), so each
//    XCD's random-gather working set (25.6/8 = 3.2 MB) fits its private L2.

constexpr int N_NODES = 100000;
constexpr int EMB     = 64;
constexpr int FANOUT  = 16;

typedef __attribute__((ext_vector_type(8))) short short8;
typedef __attribute__((ext_vector_type(4))) float f32x4;

__device__ inline unsigned short bf16_rne(float f) {
    unsigned u = __float_as_uint(f);
    return (unsigned short)((u + 0x7fffu + ((u >> 16) & 1u)) >> 16);
}
__device__ inline float bf16_tof(unsigned short s) {
    return __uint_as_float(((unsigned)s) << 16);
}

// ---- weights -> Bck hi/lo bf16, layout [c][k], c in [0,2*D_OUT), k in [0,D_IN) ----
__global__ __launch_bounds__(256)
void prep_Bck(const float* __restrict__ W, unsigned short* __restrict__ Bhi,
              unsigned short* __restrict__ Blo, int D_IN, int D_OUT)
{
    int i = blockIdx.x * 256 + threadIdx.x;
    int total = 2 * D_OUT * D_IN;
    if (i >= total) return;
    int c = i / D_IN, k = i % D_IN;
    float v = (c < D_OUT) ? W[(size_t)c * (2 * D_IN) + k]
                          : W[(size_t)(c - D_OUT) * (2 * D_IN) + D_IN + k];
    unsigned short hi = bf16_rne(v);
    Bhi[i] = hi;
    Blo[i] = bf16_rne(v - bf16_tof(hi));
}

// ---- MFMA GEMM: g[n][c] = sum_k h[n][k] * Bck[c][k] ----
// block = 128 nodes x C cols; 4 waves in 2x2 -> wave tile 64 x (C/2).
// SPLIT_A: read fp32 h, split hi/lo at staging (layer 1).
// else:    read pre-split bf16 planes (layers 2-4), b128 copy staging.
template<int K, int C, bool SPLIT_A>
__global__ __launch_bounds__(256, 2)
void mfma_gemm(const float* __restrict__ hf,
               const unsigned short* __restrict__ hHi,
               const unsigned short* __restrict__ hLo,
               const unsigned short* __restrict__ Bhi,
               const unsigned short* __restrict__ Blo,
               float* __restrict__ g_self,
               unsigned short* __restrict__ g_neigh, int N)
{
    constexpr int DO  = C / 2;
    constexpr int NI  = C / 32;            // 16-col subtiles per wave
    constexpr int LDA = 40;                // 80B row stride: b128 reads 2-way (free)
    __shared__ unsigned short Ah[128 * LDA], Al[128 * LDA];
    __shared__ unsigned short Bh[C * LDA],  Bl[C * LDA];

    const int tid   = threadIdx.x;
    const int wave  = tid >> 6;
    const int lane  = tid & 63;
    const int ml    = lane & 15;
    const int quad  = lane >> 4;
    const int wr    = wave >> 1;           // wave row (0/1): 64 nodes each
    const int wc    = wave & 1;            // wave col (0/1): C/2 cols each
    const int node0 = blockIdx.x * 128;

    f32x4 acc[4][NI];
    #pragma unroll
    for (int mi = 0; mi < 4; ++mi)
        #pragma unroll
        for (int ni = 0; ni < NI; ++ni)
            acc[mi][ni] = (f32x4){0.f, 0.f, 0.f, 0.f};

    for (int k0 = 0; k0 < K; k0 += 32) {
        // ---- stage A: 128 rows x 32 k, 2 planes ----
        if (SPLIT_A) {
            // 1024 float4 over [row(128)][c4(8)]
            #pragma unroll
            for (int t = 0; t < 4; ++t) {
                int idx = tid + t * 256;
                int row = idx >> 3, c4 = idx & 7;
                float4 v = make_float4(0.f, 0.f, 0.f, 0.f);
                if (node0 + row < N)
                    v = *(const float4*)&hf[(size_t)(node0 + row) * K + k0 + c4 * 4];
                float vv[4] = {v.x, v.y, v.z, v.w};
                unsigned short hi[4], lo[4];
                #pragma unroll
                for (int e = 0; e < 4; ++e) {
                    hi[e] = bf16_rne(vv[e]);
                    lo[e] = bf16_rne(vv[e] - bf16_tof(hi[e]));
                }
                *(uint2*)&Ah[row * LDA + c4 * 4] = *(const uint2*)hi;
                *(uint2*)&Al[row * LDA + c4 * 4] = *(const uint2*)lo;
            }
        } else {
            // 1024 uint4 over [plane(2)][row(128)][ch(4)]
            #pragma unroll
            for (int t = 0; t < 4; ++t) {
                int idx = tid + t * 256;
                int pl  = idx >> 9;
                int row = (idx >> 2) & 127;
                int ch  = idx & 3;
                const unsigned short* src =
                    (pl ? hLo : hHi) + (size_t)(node0 + row) * K + k0 + ch * 8;
                unsigned short* dst = (pl ? Al : Ah) + row * LDA + ch * 8;
                *(uint4*)dst = *(const uint4*)src;
            }
        }
        // ---- stage B: C rows x 32 k, 2 planes: 2*C*4 uint4 ----
        {
            constexpr int BQ = C * 4;
            #pragma unroll
            for (int t = 0; t < (2 * BQ) / 256; ++t) {
                int idx = tid + t * 256;
                int pl  = idx / BQ;
                int rem = idx % BQ;
                int row = rem >> 2;
                int ch  = rem & 3;
                const unsigned short* src =
                    (pl ? Blo : Bhi) + (size_t)row * K + k0 + ch * 8;
                unsigned short* dst = (pl ? Bl : Bh) + row * LDA + ch * 8;
                *(uint4*)dst = *(const uint4*)src;
            }
        }
        __syncthreads();

        short8 afh[4], afl[4];
        #pragma unroll
        for (int mi = 0; mi < 4; ++mi) {
            int r = wr * 64 + mi * 16 + ml;
            afh[mi] = *(const short8*)&Ah[r * LDA + quad * 8];
            afl[mi] = *(const short8*)&Al[r * LDA + quad * 8];
        }
        #pragma unroll
        for (int ni = 0; ni < NI; ++ni) {
            int c = wc * (C / 2) + ni * 16 + ml;
            short8 bh = *(const short8*)&Bh[c * LDA + quad * 8];
            short8 bl = *(const short8*)&Bl[c * LDA + quad * 8];
            #pragma unroll
            for (int mi = 0; mi < 4; ++mi) {
                acc[mi][ni] = __builtin_amdgcn_mfma_f32_16x16x32_bf16(afl[mi], bh, acc[mi][ni], 0, 0, 0);
                acc[mi][ni] = __builtin_amdgcn_mfma_f32_16x16x32_bf16(afh[mi], bl, acc[mi][ni], 0, 0, 0);
                acc[mi][ni] = __builtin_amdgcn_mfma_f32_16x16x32_bf16(afh[mi], bh, acc[mi][ni], 0, 0, 0);
            }
        }
        __syncthreads();
    }

    // epilogue: row = quad*4+r, col = ml (verified layout)
    #pragma unroll
    for (int mi = 0; mi < 4; ++mi) {
        #pragma unroll
        for (int r = 0; r < 4; ++r) {
            int node = node0 + wr * 64 + mi * 16 + quad * 4 + r;
            if (node >= N) continue;
            #pragma unroll
            for (int ni = 0; ni < NI; ++ni) {
                int c = wc * (C / 2) + ni * 16 + ml;
                float v = acc[mi][ni][r];
                if (c < DO)
                    g_self[(size_t)node * DO + c] = v;
                else
                    g_neigh[(size_t)node * DO + (c - DO)] = bf16_rne(v);
            }
        }
    }
}

// ---- aggregation, XCD-column-sharded ----
// block b: col group cg = b&7 (8 or 16 cols), node slice = b>>3.
// PLANES_OUT: write bf16 hi/lo planes; else fp32 (in-place over g_self is OK:
// each thread reads exactly the addresses it later writes).
template<int D_OUT, bool PLANES_OUT>
__global__ __launch_bounds__(256)
void aggregate(const float* __restrict__ gs,
               const unsigned short* __restrict__ gn,
               const int* __restrict__ neigh,
               unsigned short* __restrict__ outH,
               unsigned short* __restrict__ outL,
               float* __restrict__ outF, int N)
{
    constexpr int LPN = (D_OUT == 128) ? 2 : 1;   // lanes per node (8 cols each)
    constexpr int NPB = 256 / LPN;
    const int cg    = blockIdx.x & 7;
    const int slice = blockIdx.x >> 3;
    const int tid   = threadIdx.x;
    const int node  = slice * NPB + tid / LPN;
    const int p     = tid % LPN;
    const int c0    = cg * (8 * LPN) + p * 8;
    if (node >= N) return;

    const int4* nb4 = (const int4*)(neigh + (size_t)node * FANOUT);
    int4 q0 = nb4[0], q1 = nb4[1], q2 = nb4[2], q3 = nb4[3];
    int ids[FANOUT] = {q0.x, q0.y, q0.z, q0.w, q1.x, q1.y, q1.z, q1.w,
                       q2.x, q2.y, q2.z, q2.w, q3.x, q3.y, q3.z, q3.w};

    float acc[8];
    #pragma unroll
    for (int c = 0; c < 8; ++c) acc[c] = 0.f;
    #pragma unroll
    for (int j = 0; j < FANOUT; ++j) {
        uint4 q = *(const uint4*)&gn[(size_t)ids[j] * D_OUT + c0];
        acc[0] += __uint_as_float(q.x << 16);
        acc[1] += __uint_as_float(q.x & 0xffff0000u);
        acc[2] += __uint_as_float(q.y << 16);
        acc[3] += __uint_as_float(q.y & 0xffff0000u);
        acc[4] += __uint_as_float(q.z << 16);
        acc[5] += __uint_as_float(q.z & 0xffff0000u);
        acc[6] += __uint_as_float(q.w << 16);
        acc[7] += __uint_as_float(q.w & 0xffff0000u);
    }
    const float inv = 1.0f / (float)FANOUT;
    const float* s = gs + (size_t)node * D_OUT + c0;
    float4 s0 = *(const float4*)&s[0];
    float4 s1 = *(const float4*)&s[4];
    float o[8];
    o[0] = fmaxf(fmaf(acc[0], inv, s0.x), 0.f);
    o[1] = fmaxf(fmaf(acc[1], inv, s0.y), 0.f);
    o[2] = fmaxf(fmaf(acc[2], inv, s0.z), 0.f);
    o[3] = fmaxf(fmaf(acc[3], inv, s0.w), 0.f);
    o[4] = fmaxf(fmaf(acc[4], inv, s1.x), 0.f);
    o[5] = fmaxf(fmaf(acc[5], inv, s1.y), 0.f);
    o[6] = fmaxf(fmaf(acc[6], inv, s1.z), 0.f);
    o[7] = fmaxf(fmaf(acc[7], inv, s1.w), 0.f);

    if (PLANES_OUT) {
        alignas(16) unsigned short hi[8], lo[8];
        #pragma unroll
        for (int c = 0; c < 8; ++c) {
            hi[c] = bf16_rne(o[c]);
            lo[c] = bf16_rne(o[c] - bf16_tof(hi[c]));
        }
        *(uint4*)&outH[(size_t)node * D_OUT + c0] = *(const uint4*)hi;
        *(uint4*)&outL[(size_t)node * D_OUT + c0] = *(const uint4*)lo;
    } else {
        float* op = outF + (size_t)node * D_OUT + c0;
        *(float4*)&op[0] = make_float4(o[0], o[1], o[2], o[3]);
        *(float4*)&op[4] = make_float4(o[4], o[5], o[6], o[7]);
    }
}

// ---- final gather: out[i] = h4[nodes[i]] ----
__global__ __launch_bounds__(256)
void gather_out(const float* __restrict__ h4, const int* __restrict__ nodes,
                float* __restrict__ out, int N)
{
    constexpr int E4 = EMB / 4;
    int i = blockIdx.x * blockDim.x + threadIdx.x;
    if (i < N * E4) {
        int n = i / E4;
        int e = i % E4;
        int src = nodes[n];
        ((float4*)out)[(size_t)n * E4 + e] =
            ((const float4*)h4)[(size_t)src * E4 + e];
    }
}

extern "C" void kernel_launch(void* const* d_in, const int* in_sizes, int n_in,
                              void* d_out, int out_size, void* d_ws, size_t ws_size,
                              hipStream_t stream)
{
    const float* features = (const float*)d_in[0];
    const float* W1       = (const float*)d_in[1];
    const float* W2       = (const float*)d_in[2];
    const float* W3       = (const float*)d_in[3];
    const float* W4       = (const float*)d_in[4];
    const int*   nodes    = (const int*)d_in[5];
    const int*   neigh    = (const int*)d_in[6];
    float*       out      = (float*)d_out;

    // ws layout (order matters: staging overruns past N rows spill into the
    // next region, which is allocated): B planes, hH, hL, gs, gn.
    unsigned short* B1h = (unsigned short*)d_ws;        // 65536
    unsigned short* B1l = B1h + 65536;
    unsigned short* B2h = B1l + 65536;                  // 32768
    unsigned short* B2l = B2h + 32768;
    unsigned short* B3h = B2l + 32768;
    unsigned short* B3l = B3h + 32768;
    unsigned short* B4h = B3l + 32768;                  // 16384
    unsigned short* B4l = B4h + 16384;
    unsigned short* hH  = B4l + 16384;                  // N*128 bf16
    unsigned short* hL  = hH + (size_t)N_NODES * 128;   // N*128 bf16
    float* gs = (float*)(hL + (size_t)N_NODES * 128);   // N*128 fp32
    unsigned short* gn = (unsigned short*)(gs + (size_t)N_NODES * 128); // N*128 bf16

    prep_Bck<<<(65536 + 255) / 256, 256, 0, stream>>>(W1, B1h, B1l, 256, 128);
    prep_Bck<<<(32768 + 255) / 256, 256, 0, stream>>>(W2, B2h, B2l, 128, 128);
    prep_Bck<<<(32768 + 255) / 256, 256, 0, stream>>>(W3, B3h, B3l, 128, 128);
    prep_Bck<<<(16384 + 255) / 256, 256, 0, stream>>>(W4, B4h, B4l, 128, 64);

    const int gemm_grid = (N_NODES + 127) / 128;          // 782
    const int agg_grid_128 = ((N_NODES + 127) / 128) * 8; // 6256
    const int agg_grid_64  = ((N_NODES + 255) / 256) * 8; // 3128

    // L1: fp32 features, in-kernel split
    mfma_gemm<256, 256, true><<<gemm_grid, 256, 0, stream>>>(
        features, nullptr, nullptr, B1h, B1l, gs, gn, N_NODES);
    aggregate<128, true><<<agg_grid_128, 256, 0, stream>>>(
        gs, gn, neigh, hH, hL, nullptr, N_NODES);
    // L2
    mfma_gemm<128, 256, false><<<gemm_grid, 256, 0, stream>>>(
        nullptr, hH, hL, B2h, B2l, gs, gn, N_NODES);
    aggregate<128, true><<<agg_grid_128, 256, 0, stream>>>(
        gs, gn, neigh, hH, hL, nullptr, N_NODES);
    // L3
    mfma_gemm<128, 256, false><<<gemm_grid, 256, 0, stream>>>(
        nullptr, hH, hL, B3h, B3l, gs, gn, N_NODES);
    aggregate<128, true><<<agg_grid_128, 256, 0, stream>>>(
        gs, gn, neigh, hH, hL, nullptr, N_NODES);
    // L4: C=128 (D_OUT=64); aggregate writes fp32 in-place over g_self
    mfma_gemm<128, 128, false><<<gemm_grid, 256, 0, stream>>>(
        nullptr, hH, hL, B4h, B4l, gs, gn, N_NODES);
    aggregate<64, false><<<agg_grid_64, 256, 0, stream>>>(
        gs, gn, neigh, nullptr, nullptr, gs, N_NODES);

    gather_out<<<(N_NODES * (EMB / 4) + 255) / 256, 256, 0, stream>>>(gs, nodes, out, N_NODES);
}

// Round 5
// 509.979 us; speedup vs baseline: 2.2919x; 2.2919x over previous
//
#include <hip/hip_runtime.h>
#include <hip/hip_bf16.h>

// GraphSAGE R5: aggregate fused INTO the next layer's GEMM.
//   gemm1:  g1 = features @ B1^T                     (dense, K=256, C=256)
//   fused:  h  = relu(gs + mean_j gn[nb[j]])  (A-phase, full-row gathers)
//           g' = h @ B^T                              (split-bf16 MFMA)
//   agg_out: out[i] = relu(gs4[nodes[i]] + mean gn4[nb]) -> d_out
// Split-bf16 3-product GEMM (fp32-grade). gs updated in-place (blocks only
// touch their own rows); gn ping-pongs. Full-row gathers only (R4 lesson:
// cache residency is line-granular; column sharding amplified fetch 8x).

constexpr int N_NODES = 100000;
constexpr int FANOUT  = 16;

typedef __attribute__((ext_vector_type(8))) short short8;
typedef __attribute__((ext_vector_type(4))) float f32x4;

__device__ inline unsigned short bf16_rne(float f) {
    unsigned u = __float_as_uint(f);
    return (unsigned short)((u + 0x7fffu + ((u >> 16) & 1u)) >> 16);
}
__device__ inline float bf16_tof(unsigned short s) {
    return __uint_as_float(((unsigned)s) << 16);
}

// ---- weights -> Bck hi/lo bf16, layout [c][k], c in [0,2*D_OUT), k in [0,D_IN) ----
__global__ __launch_bounds__(256)
void prep_Bck(const float* __restrict__ W, unsigned short* __restrict__ Bhi,
              unsigned short* __restrict__ Blo, int D_IN, int D_OUT)
{
    int i = blockIdx.x * 256 + threadIdx.x;
    int total = 2 * D_OUT * D_IN;
    if (i >= total) return;
    int c = i / D_IN, k = i % D_IN;
    float v = (c < D_OUT) ? W[(size_t)c * (2 * D_IN) + k]
                          : W[(size_t)(c - D_OUT) * (2 * D_IN) + D_IN + k];
    unsigned short hi = bf16_rne(v);
    Bhi[i] = hi;
    Blo[i] = bf16_rne(v - bf16_tof(hi));
}

// ---- gemm1: dense, K=256, C=256. block = 64 nodes, wave tile 64x64. ----
__global__ __launch_bounds__(256, 3)
void gemm1(const float* __restrict__ hf,
           const unsigned short* __restrict__ Bhi,
           const unsigned short* __restrict__ Blo,
           float* __restrict__ gs, unsigned short* __restrict__ gn, int N)
{
    constexpr int K = 256, C = 256, DO = 128, LDA = 40, LDB = 40;
    __shared__ unsigned short Ah[64 * LDA], Al[64 * LDA];
    __shared__ unsigned short Bh[C * LDB], Bl[C * LDB];

    const int tid  = threadIdx.x;
    const int wave = tid >> 6;
    const int lane = tid & 63;
    const int ml   = lane & 15;
    const int quad = lane >> 4;
    const int node0 = blockIdx.x * 64;

    f32x4 acc[4][4];
    #pragma unroll
    for (int mi = 0; mi < 4; ++mi)
        #pragma unroll
        for (int ni = 0; ni < 4; ++ni)
            acc[mi][ni] = (f32x4){0.f, 0.f, 0.f, 0.f};

    for (int k0 = 0; k0 < K; k0 += 32) {
        // A: 64 rows x 32 k fp32 -> split planes (512 float4, 2/thread)
        #pragma unroll
        for (int t = 0; t < 2; ++t) {
            int idx = tid + t * 256;
            int row = idx >> 3, c4 = idx & 7;
            int nd = node0 + row; if (nd >= N) nd = N - 1;
            float4 v = *(const float4*)&hf[(size_t)nd * K + k0 + c4 * 4];
            float vv[4] = {v.x, v.y, v.z, v.w};
            unsigned short hi[4], lo[4];
            #pragma unroll
            for (int e = 0; e < 4; ++e) {
                hi[e] = bf16_rne(vv[e]);
                lo[e] = bf16_rne(vv[e] - bf16_tof(hi[e]));
            }
            *(uint2*)&Ah[row * LDA + c4 * 4] = *(const uint2*)hi;
            *(uint2*)&Al[row * LDA + c4 * 4] = *(const uint2*)lo;
        }
        // B: 2 planes x 256 rows x 4 chunks (2048 uint4, 8/thread)
        #pragma unroll
        for (int t = 0; t < 8; ++t) {
            int idx = tid + t * 256;
            int pl  = idx >> 10;
            int rem = idx & 1023;
            int row = rem >> 2, ch = rem & 3;
            const unsigned short* src = (pl ? Blo : Bhi) + (size_t)row * K + k0 + ch * 8;
            unsigned short* dst = (pl ? Bl : Bh) + row * LDB + ch * 8;
            *(uint4*)dst = *(const uint4*)src;
        }
        __syncthreads();

        short8 afh[4], afl[4];
        #pragma unroll
        for (int mi = 0; mi < 4; ++mi) {
            int r = mi * 16 + ml;
            afh[mi] = *(const short8*)&Ah[r * LDA + quad * 8];
            afl[mi] = *(const short8*)&Al[r * LDA + quad * 8];
        }
        #pragma unroll
        for (int ni = 0; ni < 4; ++ni) {
            int c = wave * 64 + ni * 16 + ml;
            short8 bh = *(const short8*)&Bh[c * LDB + quad * 8];
            short8 bl = *(const short8*)&Bl[c * LDB + quad * 8];
            #pragma unroll
            for (int mi = 0; mi < 4; ++mi) {
                acc[mi][ni] = __builtin_amdgcn_mfma_f32_16x16x32_bf16(afl[mi], bh, acc[mi][ni], 0, 0, 0);
                acc[mi][ni] = __builtin_amdgcn_mfma_f32_16x16x32_bf16(afh[mi], bl, acc[mi][ni], 0, 0, 0);
                acc[mi][ni] = __builtin_amdgcn_mfma_f32_16x16x32_bf16(afh[mi], bh, acc[mi][ni], 0, 0, 0);
            }
        }
        __syncthreads();
    }

    #pragma unroll
    for (int mi = 0; mi < 4; ++mi)
        #pragma unroll
        for (int r = 0; r < 4; ++r) {
            int node = node0 + mi * 16 + quad * 4 + r;
            if (node >= N) continue;
            #pragma unroll
            for (int ni = 0; ni < 4; ++ni) {
                int c = wave * 64 + ni * 16 + ml;
                float v = acc[mi][ni][r];
                if (c < DO) gs[(size_t)node * DO + c] = v;
                else        gn[(size_t)node * DO + (c - DO)] = bf16_rne(v);
            }
        }
}

// ---- fused layer: A-phase aggregate (full-row gathers) + MFMA GEMM ----
// D_IN=128 fixed. C=256 (DO=128) or C=128 (DO=64).
template<int C>
__global__ __launch_bounds__(256, 2)
void fused_layer(const float* __restrict__ gs_in,
                 const unsigned short* __restrict__ gn_in,
                 const int* __restrict__ neigh,
                 const unsigned short* __restrict__ Bhi,
                 const unsigned short* __restrict__ Blo,
                 float* __restrict__ gs_out,
                 unsigned short* __restrict__ gn_out, int N)
{
    constexpr int K = 128, DO = C / 2, NI = C / 64, LDAF = 136, LDB = 40;
    __shared__ unsigned short Afh[64 * LDAF], Afl[64 * LDAF];
    __shared__ unsigned short Bh[C * LDB], Bl[C * LDB];

    const int tid  = threadIdx.x;
    const int wave = tid >> 6;
    const int lane = tid & 63;
    const int ml   = lane & 15;
    const int quad = lane >> 4;
    const int node0 = blockIdx.x * 64;

    // ---- A-phase: h = relu(gs + mean*gn[nb]), split hi/lo into LDS ----
    {
        const int row = tid >> 2;          // node within block
        const int seg = tid & 3;           // 32-col segment
        int nd = node0 + row; if (nd >= N) nd = N - 1;
        const int4* nb4 = (const int4*)(neigh + (size_t)nd * FANOUT);
        int4 q0 = nb4[0], q1 = nb4[1], q2 = nb4[2], q3 = nb4[3];
        int ids[FANOUT] = {q0.x, q0.y, q0.z, q0.w, q1.x, q1.y, q1.z, q1.w,
                           q2.x, q2.y, q2.z, q2.w, q3.x, q3.y, q3.z, q3.w};
        float acc[32];
        #pragma unroll
        for (int c = 0; c < 32; ++c) acc[c] = 0.f;
        #pragma unroll
        for (int j = 0; j < FANOUT; ++j) {
            const uint4* src = (const uint4*)&gn_in[(size_t)ids[j] * 128 + seg * 32];
            #pragma unroll
            for (int t = 0; t < 4; ++t) {
                uint4 q = src[t];
                acc[t*8+0] += __uint_as_float(q.x << 16);
                acc[t*8+1] += __uint_as_float(q.x & 0xffff0000u);
                acc[t*8+2] += __uint_as_float(q.y << 16);
                acc[t*8+3] += __uint_as_float(q.y & 0xffff0000u);
                acc[t*8+4] += __uint_as_float(q.z << 16);
                acc[t*8+5] += __uint_as_float(q.z & 0xffff0000u);
                acc[t*8+6] += __uint_as_float(q.w << 16);
                acc[t*8+7] += __uint_as_float(q.w & 0xffff0000u);
            }
        }
        const float inv = 1.0f / (float)FANOUT;
        alignas(16) unsigned short th[32], tl[32];
        const float4* gsp = (const float4*)&gs_in[(size_t)nd * 128 + seg * 32];
        #pragma unroll
        for (int t = 0; t < 8; ++t) {
            float4 s = gsp[t];
            float sv[4] = {s.x, s.y, s.z, s.w};
            #pragma unroll
            for (int e = 0; e < 4; ++e) {
                float h = fmaxf(fmaf(acc[t*4+e], inv, sv[e]), 0.f);
                unsigned short hi = bf16_rne(h);
                th[t*4+e] = hi;
                tl[t*4+e] = bf16_rne(h - bf16_tof(hi));
            }
        }
        #pragma unroll
        for (int t = 0; t < 4; ++t) {
            *(uint4*)&Afh[row * LDAF + seg * 32 + t * 8] = *(const uint4*)&th[t * 8];
            *(uint4*)&Afl[row * LDAF + seg * 32 + t * 8] = *(const uint4*)&tl[t * 8];
        }
    }

    f32x4 acc[4][NI];
    #pragma unroll
    for (int mi = 0; mi < 4; ++mi)
        #pragma unroll
        for (int ni = 0; ni < NI; ++ni)
            acc[mi][ni] = (f32x4){0.f, 0.f, 0.f, 0.f};

    for (int k0 = 0; k0 < K; k0 += 32) {
        // stage B k-tile: 2 planes x C rows x 4 chunks
        constexpr int TOT = 2 * C * 4;
        #pragma unroll
        for (int t = 0; t < TOT / 256; ++t) {
            int idx = tid + t * 256;
            int pl  = idx / (C * 4);
            int rem = idx % (C * 4);
            int row = rem >> 2, ch = rem & 3;
            const unsigned short* src = (pl ? Blo : Bhi) + (size_t)row * K + k0 + ch * 8;
            unsigned short* dst = (pl ? Bl : Bh) + row * LDB + ch * 8;
            *(uint4*)dst = *(const uint4*)src;
        }
        __syncthreads();

        short8 afh[4], afl[4];
        #pragma unroll
        for (int mi = 0; mi < 4; ++mi) {
            int r = mi * 16 + ml;
            afh[mi] = *(const short8*)&Afh[r * LDAF + k0 + quad * 8];
            afl[mi] = *(const short8*)&Afl[r * LDAF + k0 + quad * 8];
        }
        #pragma unroll
        for (int ni = 0; ni < NI; ++ni) {
            int c = wave * (16 * NI) + ni * 16 + ml;
            short8 bh = *(const short8*)&Bh[c * LDB + quad * 8];
            short8 bl = *(const short8*)&Bl[c * LDB + quad * 8];
            #pragma unroll
            for (int mi = 0; mi < 4; ++mi) {
                acc[mi][ni] = __builtin_amdgcn_mfma_f32_16x16x32_bf16(afl[mi], bh, acc[mi][ni], 0, 0, 0);
                acc[mi][ni] = __builtin_amdgcn_mfma_f32_16x16x32_bf16(afh[mi], bl, acc[mi][ni], 0, 0, 0);
                acc[mi][ni] = __builtin_amdgcn_mfma_f32_16x16x32_bf16(afh[mi], bh, acc[mi][ni], 0, 0, 0);
            }
        }
        __syncthreads();
    }

    #pragma unroll
    for (int mi = 0; mi < 4; ++mi)
        #pragma unroll
        for (int r = 0; r < 4; ++r) {
            int node = node0 + mi * 16 + quad * 4 + r;
            if (node >= N) continue;
            #pragma unroll
            for (int ni = 0; ni < NI; ++ni) {
                int c = wave * (16 * NI) + ni * 16 + ml;
                float v = acc[mi][ni][r];
                if (c < DO) gs_out[(size_t)node * DO + c] = v;
                else        gn_out[(size_t)node * DO + (c - DO)] = bf16_rne(v);
            }
        }
}

// ---- final: out[i] = relu(gs4[nodes[i]] + mean_j gn4[nb[j]]), D_OUT=64 ----
__global__ __launch_bounds__(256)
void agg_out(const float* __restrict__ gs4, const unsigned short* __restrict__ gn4,
             const int* __restrict__ neigh, const int* __restrict__ nodes,
             float* __restrict__ out, int N)
{
    const int i    = blockIdx.x * 32 + (threadIdx.x >> 3);
    const int lane = threadIdx.x & 7;
    if (i >= N) return;
    const int nd = nodes[i];
    const int4* nb4 = (const int4*)(neigh + (size_t)nd * FANOUT);
    int4 q0 = nb4[0], q1 = nb4[1], q2 = nb4[2], q3 = nb4[3];
    int ids[FANOUT] = {q0.x, q0.y, q0.z, q0.w, q1.x, q1.y, q1.z, q1.w,
                       q2.x, q2.y, q2.z, q2.w, q3.x, q3.y, q3.z, q3.w};
    float acc[8];
    #pragma unroll
    for (int c = 0; c < 8; ++c) acc[c] = 0.f;
    #pragma unroll
    for (int j = 0; j < FANOUT; ++j) {
        uint4 q = *(const uint4*)&gn4[(size_t)ids[j] * 64 + lane * 8];
        acc[0] += __uint_as_float(q.x << 16);
        acc[1] += __uint_as_float(q.x & 0xffff0000u);
        acc[2] += __uint_as_float(q.y << 16);
        acc[3] += __uint_as_float(q.y & 0xffff0000u);
        acc[4] += __uint_as_float(q.z << 16);
        acc[5] += __uint_as_float(q.z & 0xffff0000u);
        acc[6] += __uint_as_float(q.w << 16);
        acc[7] += __uint_as_float(q.w & 0xffff0000u);
    }
    const float inv = 1.0f / (float)FANOUT;
    const float* s = gs4 + (size_t)nd * 64 + lane * 8;
    float4 s0 = *(const float4*)&s[0];
    float4 s1 = *(const float4*)&s[4];
    float4 o0, o1;
    o0.x = fmaxf(fmaf(acc[0], inv, s0.x), 0.f);
    o0.y = fmaxf(fmaf(acc[1], inv, s0.y), 0.f);
    o0.z = fmaxf(fmaf(acc[2], inv, s0.z), 0.f);
    o0.w = fmaxf(fmaf(acc[3], inv, s0.w), 0.f);
    o1.x = fmaxf(fmaf(acc[4], inv, s1.x), 0.f);
    o1.y = fmaxf(fmaf(acc[5], inv, s1.y), 0.f);
    o1.z = fmaxf(fmaf(acc[6], inv, s1.z), 0.f);
    o1.w = fmaxf(fmaf(acc[7], inv, s1.w), 0.f);
    float* op = out + (size_t)i * 64 + lane * 8;
    *(float4*)&op[0] = o0;
    *(float4*)&op[4] = o1;
}

extern "C" void kernel_launch(void* const* d_in, const int* in_sizes, int n_in,
                              void* d_out, int out_size, void* d_ws, size_t ws_size,
                              hipStream_t stream)
{
    const float* features = (const float*)d_in[0];
    const float* W1       = (const float*)d_in[1];
    const float* W2       = (const float*)d_in[2];
    const float* W3       = (const float*)d_in[3];
    const float* W4       = (const float*)d_in[4];
    const int*   nodes    = (const int*)d_in[5];
    const int*   neigh    = (const int*)d_in[6];
    float*       out      = (float*)d_out;

    unsigned short* B1h = (unsigned short*)d_ws;       // 65536
    unsigned short* B1l = B1h + 65536;
    unsigned short* B2h = B1l + 65536;                 // 32768
    unsigned short* B2l = B2h + 32768;
    unsigned short* B3h = B2l + 32768;
    unsigned short* B3l = B3h + 32768;
    unsigned short* B4h = B3l + 32768;                 // 16384
    unsigned short* B4l = B4h + 16384;
    float* gs = (float*)(B4l + 16384);                 // N*128 fp32, in-place L1-L3
    unsigned short* gnA = (unsigned short*)(gs + (size_t)N_NODES * 128); // N*128 bf16
    unsigned short* gnB = gnA + (size_t)N_NODES * 128; // N*128 bf16
    float* gs4 = (float*)gnB;                          // aliases gnB (free at L4)
    unsigned short* gn4 = gnB + (size_t)N_NODES * 128; // N*64 bf16

    prep_Bck<<<(65536 + 255) / 256, 256, 0, stream>>>(W1, B1h, B1l, 256, 128);
    prep_Bck<<<(32768 + 255) / 256, 256, 0, stream>>>(W2, B2h, B2l, 128, 128);
    prep_Bck<<<(32768 + 255) / 256, 256, 0, stream>>>(W3, B3h, B3l, 128, 128);
    prep_Bck<<<(16384 + 255) / 256, 256, 0, stream>>>(W4, B4h, B4l, 128, 64);

    const int grid = (N_NODES + 63) / 64;   // 1563

    gemm1<<<grid, 256, 0, stream>>>(features, B1h, B1l, gs, gnA, N_NODES);
    fused_layer<256><<<grid, 256, 0, stream>>>(gs, gnA, neigh, B2h, B2l, gs, gnB, N_NODES);
    fused_layer<256><<<grid, 256, 0, stream>>>(gs, gnB, neigh, B3h, B3l, gs, gnA, N_NODES);
    fused_layer<128><<<grid, 256, 0, stream>>>(gs, gnA, neigh, B4h, B4l, gs4, gn4, N_NODES);
    agg_out<<<(N_NODES + 31) / 32, 256, 0, stream>>>(gs4, gn4, neigh, nodes, out, N_NODES);
}